// Round 4
// baseline (253.976 us; speedup 1.0000x reference)
//
#include <hip/hip_runtime.h>
#include <hip/hip_bf16.h>

// PatchConv2d: out[b,o,h,w] = conv3x3(x,kernel) + 0.1*(h+w)*patch_sum[b,h,w] + bias[o]
// x:(16,64,128,128) f32, kernel:(128,64,3,3) f32, bias:(128,) f32 -> out(16,128,128,128) f32
//
// R4: prep_x v2 (vectorized NCHW->NHWC bf16 transpose + channel-sum image S),
// weights in per-tap [tap][kc][oc][32ci] bf16 (B-frags from L2, no LDS),
// conv_main processes TWO output rows per block (M=256) staging 4 halo rows
// once -> 2304 MFMA per barrier, B-frags reused across both rows.

typedef __attribute__((ext_vector_type(8))) short short8;
typedef __attribute__((ext_vector_type(4))) float f32x4;

#define B_COEF 0.1f
constexpr int CI = 64, CO = 128, H = 128, W = 128;
constexpr int XPAD = 72;  // LDS row stride (elems) for xrow

static __device__ inline short bf16s(float v) {
    __hip_bfloat16 b = __float2bfloat16(v);
    return *reinterpret_cast<short*>(&b);
}

// ---- x NCHW f32 -> xt NHWC bf16 ; S[b][h][w] = sum_ci x (fp32) -------------
__global__ __launch_bounds__(256)
void prep_x(const float* __restrict__ x, __hip_bfloat16* __restrict__ xt,
            float* __restrict__ S) {
    __shared__ float tile[64 * 132];
    const int h = blockIdx.x, b = blockIdx.y, tid = threadIdx.x;

    // load: 32 lanes cover one ci row (512 B contiguous), 8 iters over ci
    const int w4 = (tid & 31) * 4;
    const int ci0 = tid >> 5;  // 0..7
#pragma unroll
    for (int it = 0; it < 8; ++it) {
        int ci = ci0 + it * 8;
        float4 v = *(const float4*)(x + (((size_t)b * CI + ci) * H + h) * W + w4);
        *(float4*)&tile[ci * 132 + w4] = v;
    }
    __syncthreads();

    // transpose out: thread = (w, ci-half); pack 32 bf16, sum for S
    const int w = tid >> 1, chalf = tid & 1;
    float s = 0.0f;
    short8 pk[4];
#pragma unroll
    for (int q = 0; q < 4; ++q) {
#pragma unroll
        for (int k = 0; k < 8; ++k) {
            float v = tile[(chalf * 32 + q * 8 + k) * 132 + w];
            s += v;
            pk[q][k] = bf16s(v);
        }
    }
    s += __shfl_xor(s, 1);
    if (chalf == 0) S[((size_t)b * H + h) * W + w] = s;
    __hip_bfloat16* dst = xt + (((size_t)b * H + h) * W + w) * CI + chalf * 32;
#pragma unroll
    for (int q = 0; q < 4; ++q) *(short8*)(dst + q * 8) = pk[q];
}

// ---- kernel f32 [oc][ci][3][3] -> bf16 wq[tap][kc][oc][32] (ci = kc*32+j) --
__global__ void prep_wq(const float* __restrict__ wgt, __hip_bfloat16* __restrict__ wq) {
    int idx = blockIdx.x * 256 + threadIdx.x;  // 9*128*64 = 73728
    if (idx < 9 * CO * CI) {
        int tap = idx >> 13;
        int rem = idx & 8191;
        int oc = rem >> 6, ci = rem & 63;
        int kc = ci >> 5, j = ci & 31;
        wq[(((tap * 2 + kc) * CO + oc) << 5) + j] =
            __float2bfloat16(wgt[(oc * CI + ci) * 9 + tap]);
    }
}

// ---- main: 2 output rows per block, M=256, N=128, K=9x64 -------------------
__global__ __launch_bounds__(256, 2)
void conv_main(const __hip_bfloat16* __restrict__ xt,
               const __hip_bfloat16* __restrict__ wq,
               const float* __restrict__ S,
               const float* __restrict__ bias,
               float* __restrict__ out) {
    __shared__ __hip_bfloat16 xrow[4][130 * XPAD];
    __shared__ float ssum[2][132];

    const int tid = threadIdx.x, b = blockIdx.y;
    const int h = blockIdx.x * 2;  // rows h, h+1
    const int lane = tid & 63, waveid = tid >> 6;
    const int lo16 = lane & 15, quad = lane >> 4;
    const int m0 = (waveid & 1) * 64, n0 = (waveid >> 1) * 64;

    // ---- stage 4 halo rows (h-1 .. h+2), zero-padded
    const int c8 = (tid & 7) * 8, wl = tid >> 3;
#pragma unroll
    for (int r = 0; r < 4; ++r) {
        const int gh = h - 1 + r;
#pragma unroll
        for (int it = 0; it < 5; ++it) {
            int w = wl + it * 32;
            if (w < 130) {
                int gw = w - 1;
                short8 v = {0, 0, 0, 0, 0, 0, 0, 0};
                if (gh >= 0 && gh < H && gw >= 0 && gw < W)
                    v = *(const short8*)(xt + (((size_t)b * H + gh) * W + gw) * CI + c8);
                *(short8*)&xrow[r][w * XPAD + c8] = v;
            }
        }
    }
    // ---- patch_sum precursors for both rows
    if (tid < 130) {
        int gw = tid - 1;
        float sv[4] = {0.f, 0.f, 0.f, 0.f};
        if (gw >= 0 && gw < W) {
#pragma unroll
            for (int r = 0; r < 4; ++r) {
                int gh = h - 1 + r;
                if (gh >= 0 && gh < H) sv[r] = S[((size_t)b * H + gh) * W + gw];
            }
        }
        ssum[0][tid] = sv[0] + sv[1] + sv[2];
        ssum[1][tid] = sv[1] + sv[2] + sv[3];
    }
    __syncthreads();  // the only barrier

    f32x4 acc[2][4][4] = {};

#pragma unroll
    for (int kh = 0; kh < 3; ++kh) {
#pragma unroll
        for (int kw = 0; kw < 3; ++kw) {
            const int tap = kh * 3 + kw;
            short8 bq[2][4];
#pragma unroll
            for (int kc = 0; kc < 2; ++kc)
#pragma unroll
                for (int ni = 0; ni < 4; ++ni)
                    bq[kc][ni] = *(const short8*)(
                        wq + (((tap * 2 + kc) * CO + n0 + ni * 16 + lo16) << 5) + quad * 8);
#pragma unroll
            for (int kc = 0; kc < 2; ++kc) {
                short8 af[2][4];
#pragma unroll
                for (int rr = 0; rr < 2; ++rr)
#pragma unroll
                    for (int mi = 0; mi < 4; ++mi)
                        af[rr][mi] = *(const short8*)
                            &xrow[kh + rr][(m0 + mi * 16 + lo16 + kw) * XPAD + kc * 32 + quad * 8];
#pragma unroll
                for (int rr = 0; rr < 2; ++rr)
#pragma unroll
                    for (int mi = 0; mi < 4; ++mi)
#pragma unroll
                        for (int ni = 0; ni < 4; ++ni)
                            acc[rr][mi][ni] = __builtin_amdgcn_mfma_f32_16x16x32_bf16(
                                af[rr][mi], bq[kc][ni], acc[rr][mi][ni], 0, 0, 0);
            }
        }
    }

    // ---- epilogue: + 0.1*(h+w)*patch_sum + bias; float4 stores
#pragma unroll
    for (int rr = 0; rr < 2; ++rr) {
        const int hh = h + rr;
#pragma unroll
        for (int mi = 0; mi < 4; ++mi) {
            const int wbase = m0 + mi * 16 + quad * 4;
            float cs[6];
#pragma unroll
            for (int r = 0; r < 6; ++r) cs[r] = ssum[rr][wbase + r];
            float ps[4], cf[4];
#pragma unroll
            for (int r = 0; r < 4; ++r) {
                ps[r] = cs[r] + cs[r + 1] + cs[r + 2];
                cf[r] = B_COEF * (float)(hh + wbase + r);
            }
#pragma unroll
            for (int ni = 0; ni < 4; ++ni) {
                const int oc = n0 + ni * 16 + lo16;
                const float bv = bias[oc];
                f32x4 v = acc[rr][mi][ni];
#pragma unroll
                for (int r = 0; r < 4; ++r) v[r] = v[r] + cf[r] * ps[r] + bv;
                *(f32x4*)(out + (((size_t)b * CO + oc) * H + hh) * W + wbase) = v;
            }
        }
    }
}

extern "C" void kernel_launch(void* const* d_in, const int* in_sizes, int n_in,
                              void* d_out, int out_size, void* d_ws, size_t ws_size,
                              hipStream_t stream) {
    const float* x    = (const float*)d_in[0];
    const float* wgt  = (const float*)d_in[1];
    const float* bias = (const float*)d_in[2];
    float* out = (float*)d_out;

    const size_t XT_BYTES = (size_t)16 * H * W * CI * 2;  // 33,554,432
    const size_t S_BYTES  = (size_t)16 * H * W * 4;       //  1,048,576

    __hip_bfloat16* xt = (__hip_bfloat16*)d_ws;
    float* S           = (float*)((char*)d_ws + XT_BYTES);
    __hip_bfloat16* wq = (__hip_bfloat16*)((char*)d_ws + XT_BYTES + S_BYTES);

    prep_x<<<dim3(H, 16), dim3(256), 0, stream>>>(x, xt, S);
    prep_wq<<<dim3(288), dim3(256), 0, stream>>>(wgt, wq);
    conv_main<<<dim3(H / 2, 16), dim3(256), 0, stream>>>(xt, wq, S, bias, out);
}